// Round 21
// baseline (229.001 us; speedup 1.0000x reference)
//
#include <hip/hip_runtime.h>
#include <hip/hip_fp16.h>

#define HW 65536
#define PW 256        // plane width
#define C7SD 85       // conv7 LDS row stride in DWORDS (odd -> 64 lanes hit 32 banks)
#define C5SD 73       // conv5 LDS row stride in DWORDS (odd)

// Fast exact-gelu: erf via Abramowitz-Stegun 7.1.26 (|err| <= 1.5e-7).
__device__ __forceinline__ float gelu_f(float v) {
    float ax = fabsf(v) * 0.7071067811865476f;
    float t  = 1.0f / (1.0f + 0.3275911f * ax);
    float p  = t * (0.254829592f + t * (-0.284496736f + t * (1.421413741f
             + t * (-1.453152027f + t * 1.061405429f))));
    float e  = 1.0f - p * __expf(-ax * ax);
    e = copysignf(e, v);
    return 0.5f * v * (1.0f + e);
}

__device__ __forceinline__ unsigned pack2h(float a, float b) {
    __half2 h = __floats2half2_rn(a, b);
    return *reinterpret_cast<unsigned*>(&h);
}

__device__ __forceinline__ float sgpr_f(float v) {
    union { float f; int i; } u;
    u.f = v;
    u.i = __builtin_amdgcn_readfirstlane(u.i);
    return u.f;
}

// acc(f32) += w(f32) * f16-half of h2 (packed u32), via v_fma_mix_f32 op_sel.
__device__ __forceinline__ void fma_mix_h(float& acc, float w, unsigned h2, int sel) {
    if (sel == 0)
        asm("v_fma_mix_f32 %0, %1, %2, %0 op_sel:[0,0,0] op_sel_hi:[0,1,0]"
            : "+v"(acc) : "v"(w), "v"(h2));
    else
        asm("v_fma_mix_f32 %0, %1, %2, %0 op_sel:[0,1,0] op_sel_hi:[0,1,0]"
            : "+v"(acc) : "v"(w), "v"(h2));
}

// acc(f32) += wpk.lo*pr.lo + wpk.hi*pr.hi (f16 pairs, f32 accumulate)
__device__ __forceinline__ void dot2_h(float& acc, unsigned wpk, unsigned pr) {
    asm("v_dot2_f32_f16 %0, %1, %2, %0" : "+v"(acc) : "s"(wpk), "v"(pr));
}
__device__ __forceinline__ void dot2_hv(float& acc, unsigned wpk, unsigned pr) {
    asm("v_dot2_f32_f16 %0, %1, %2, %0" : "+v"(acc) : "v"(wpk), "v"(pr));
}

// ---------------- K0: pool x over H,W (partial sums, 4 blocks per plane) ------
__global__ __launch_bounds__(256) void k_pool_x(const float* __restrict__ x,
                                                float* __restrict__ partial) {
    __shared__ float red[256];
    const int t = threadIdx.x;
    const int blk = blockIdx.x;              // plane*4 + quarter
    const float* p = x + (size_t)blk * 16384;
    float s = 0.f;
    #pragma unroll
    for (int i = 0; i < 16; ++i) {
        float4 v = *reinterpret_cast<const float4*>(p + (i * 256 + t) * 4);
        s += v.x + v.y + v.z + v.w;
    }
    red[t] = s;
    __syncthreads();
    for (int off = 128; off > 0; off >>= 1) {
        if (t < off) red[t] += red[t + off];
        __syncthreads();
    }
    if (t == 0) partial[blk] = red[0];
}

// Fused per-block routing (same reduction order as standalone k_route_mix).
__device__ __forceinline__ void route_block(const float* __restrict__ partial,
                                            const float* __restrict__ rw,
                                            const float* __restrict__ rb,
                                            const float* __restrict__ wexp,
                                            int b, int c, int taps, int parts, int t,
                                            float* pool_s, float* r_s, float* w_s) {
    if (t < 64) {
        float s = 0.f;
        for (int q = 0; q < parts; ++q) s += partial[(b * 64 + t) * parts + q];
        pool_s[t] = s * (1.0f / 65536.0f);
    }
    __syncthreads();
    if (t < 3) {
        float z = rb[t];
        #pragma unroll
        for (int i = 0; i < 64; ++i) z += pool_s[i] * rw[t * 64 + i];
        r_s[t] = 1.0f / (1.0f + expf(-z));
    }
    __syncthreads();
    if (t < taps) {
        w_s[t] = r_s[0] * wexp[(0 * 64 + c) * taps + t] +
                 r_s[1] * wexp[(1 * 64 + c) * taps + t] +
                 r_s[2] * wexp[(2 * 64 + c) * taps + t];
    }
    __syncthreads();
}

// -------- K2: depthwise 5x5 pad2 + bias + gelu -> fp16, with tile sums --------
// (R19 version: dot2 dy-pairing, fp16 LDS, odd stride — unchanged)
__global__ __launch_bounds__(256, 3) void k_conv5(const float* __restrict__ x,
                                                  const float* __restrict__ partial,
                                                  const float* __restrict__ rw,
                                                  const float* __restrict__ rb,
                                                  const float* __restrict__ wexp,
                                                  const float* __restrict__ bias,
                                                  __half* __restrict__ attn0,
                                                  float* __restrict__ tilesum) {
    __shared__ unsigned lds[68 * C5SD];      // 19856 B
    __shared__ float red[256];
    __shared__ float pool_s[64];
    __shared__ float r_s[3];
    __shared__ float w_s[25];
    const int blk = blockIdx.x;              // plane*8 + tile (64-row x 128-col)
    const int plane = blk >> 3;
    const int tile = blk & 7;
    const int b = plane >> 6;
    const int c = plane & 63;
    const int oy0 = (tile >> 1) << 6;        // 0,64,128,192
    const int ox0 = (tile & 1) << 7;         // 0,128
    const int t = threadIdx.x;
    const float* xp = x + (size_t)plane * HW;

    #pragma unroll
    for (int it = 0; it < 5; ++it) {
        const int idx = it * 256 + t;
        if (idx < 1224) {                    // 68*18
            const int lr = idx / 18;
            const int c8 = idx - lr * 18;
            const int gy = oy0 - 2 + lr;
            const int gx = ox0 - 8 + (c8 << 3);
            unsigned d0 = 0u, d1 = 0u, d2 = 0u, d3 = 0u;
            if ((unsigned)gy < 256u) {
                if ((unsigned)gx < 256u) {
                    float4 v = *reinterpret_cast<const float4*>(xp + gy * PW + gx);
                    d0 = pack2h(v.x, v.y); d1 = pack2h(v.z, v.w);
                }
                if ((unsigned)(gx + 4) < 256u) {
                    float4 v = *reinterpret_cast<const float4*>(xp + gy * PW + gx + 4);
                    d2 = pack2h(v.x, v.y); d3 = pack2h(v.z, v.w);
                }
            }
            unsigned* wp = &lds[lr * C5SD + (c8 << 2)];
            wp[0] = d0; wp[1] = d1; wp[2] = d2; wp[3] = d3;
        }
    }

    route_block(partial, rw, rb, wexp, b, c, 25, 4, t, pool_s, r_s, w_s);
    unsigned wpk[10];
    #pragma unroll
    for (int p = 0; p < 2; ++p)
        #pragma unroll
        for (int dx = 0; dx < 5; ++dx)
            wpk[p * 5 + dx] = (unsigned)__builtin_amdgcn_readfirstlane(
                (int)pack2h(w_s[(2 * p) * 5 + dx], w_s[(2 * p + 1) * 5 + dx]));
    float wt[5];
    #pragma unroll
    for (int i = 0; i < 5; ++i) wt[i] = sgpr_f(w_s[20 + i]);
    __syncthreads();

    const int tx = t & 3, ty = t >> 2;       // 4 x 64
    const int ox = tx << 5;                  // 32-wide strip: 0,32,64,96
    float acc[32];
    #pragma unroll
    for (int j = 0; j < 32; ++j) acc[j] = 0.f;

    #pragma unroll
    for (int p = 0; p < 2; ++p) {
        const int lrA = ty + 2 * p;          // dy=2p
        const unsigned* lA = &lds[lrA * C5SD + (tx << 4) + 3];
        const unsigned* lB = &lds[(lrA + 1) * C5SD + (tx << 4) + 3];
        unsigned hA[19], hB[19];
        #pragma unroll
        for (int i = 0; i < 19; ++i) hA[i] = lA[i];
        #pragma unroll
        for (int i = 0; i < 19; ++i) hB[i] = lB[i];
        unsigned pr[37];
        #pragma unroll
        for (int q = 0; q < 37; ++q)
            pr[q] = __builtin_amdgcn_perm(hB[q >> 1], hA[q >> 1],
                                          (q & 1) ? 0x07060302u : 0x05040100u);
        #pragma unroll
        for (int dx = 0; dx < 5; ++dx) {
            const unsigned wp = wpk[p * 5 + dx];
            #pragma unroll
            for (int j = 0; j < 32; ++j)
                dot2_h(acc[j], wp, pr[j + dx]);
        }
    }
    {
        const unsigned* lp = &lds[(ty + 4) * C5SD + (tx << 4) + 3];
        unsigned hbuf[19];
        #pragma unroll
        for (int i = 0; i < 19; ++i) hbuf[i] = lp[i];
        #pragma unroll
        for (int dx = 0; dx < 5; ++dx) {
            const float wv = wt[dx];
            #pragma unroll
            for (int j = 0; j < 32; ++j) {
                const int q = j + dx;
                fma_mix_h(acc[j], wv, hbuf[q >> 1], q & 1);
            }
        }
    }

    const float bs = bias[c];
    float lsum = 0.f;
    __half* op = attn0 + (size_t)plane * HW + (size_t)(oy0 + ty) * PW + ox0 + ox;
    #pragma unroll
    for (int q = 0; q < 4; ++q) {
        float g[8];
        #pragma unroll
        for (int j = 0; j < 8; ++j) {
            g[j] = gelu_f(acc[q * 8 + j] + bs);
            lsum += g[j];
        }
        uint4 st;
        st.x = pack2h(g[0], g[1]); st.y = pack2h(g[2], g[3]);
        st.z = pack2h(g[4], g[5]); st.w = pack2h(g[6], g[7]);
        *reinterpret_cast<uint4*>(op + (q << 3)) = st;
    }
    red[t] = lsum;
    __syncthreads();
    for (int off = 128; off > 0; off >>= 1) {
        if (t < off) red[t] += red[t + off];
        __syncthreads();
    }
    if (t == 0) tilesum[blk] = red[0];
}

// -------- K4: depthwise 7x7 dil3 pad9 + bias + gelu, fp16 -> fp16 -------------
// 32x128 tiles (8192 blocks): LDS 50x85dw = 17 KB -> ~8 blocks/CU (occupancy
// ceiling 100% vs 62% at 64-row tiles; measured was stuck at 38%). 8x32 map,
// 16 cols/thread; same dot2 row-pair bodies.
__global__ __launch_bounds__(256) void k_conv7(const __half* __restrict__ a0,
                                               const float* __restrict__ tilesum,
                                               const float* __restrict__ rw,
                                               const float* __restrict__ rb,
                                               const float* __restrict__ wexp,
                                               const float* __restrict__ bias,
                                               __half* __restrict__ attn1) {
    __shared__ unsigned lds[50 * C7SD];      // 17000 B
    __shared__ float pool_s[64];
    __shared__ float r_s[3];
    __shared__ float w_s[49];
    const int blk = blockIdx.x;              // plane*16 + tile (32-row x 128-col)
    const int plane = blk >> 4;
    const int tile = blk & 15;
    const int b = plane >> 6;
    const int c = plane & 63;
    const int oy0 = (tile >> 1) << 5;        // 0,32,...,224
    const int ox0 = (tile & 1) << 7;         // 0,128
    const int t = threadIdx.x;
    const __half* ap = a0 + (size_t)plane * HW;

    const uint4 z4 = make_uint4(0u, 0u, 0u, 0u);
    #pragma unroll
    for (int it = 0; it < 5; ++it) {
        const int idx = it * 256 + t;
        if (idx < 1050) {                    // 50*21
            const int lr = idx / 21;
            const int c8 = idx - lr * 21;
            const int gy = oy0 - 9 + lr;
            const int gx = ox0 - 16 + (c8 << 3);
            uint4 v = z4;
            if ((unsigned)gy < 256u && (unsigned)gx < 256u)
                v = *reinterpret_cast<const uint4*>(ap + gy * PW + gx);
            unsigned* wp = &lds[lr * C7SD + (c8 << 2)];
            wp[0] = v.x; wp[1] = v.y; wp[2] = v.z; wp[3] = v.w;
        }
    }

    route_block(tilesum, rw, rb, wexp, b, c, 49, 8, t, pool_s, r_s, w_s);
    unsigned wpk[21];
    #pragma unroll
    for (int p = 0; p < 3; ++p)
        #pragma unroll
        for (int dxi = 0; dxi < 7; ++dxi)
            wpk[p * 7 + dxi] = (unsigned)__builtin_amdgcn_readfirstlane(
                (int)pack2h(w_s[(2 * p) * 7 + dxi], w_s[(2 * p + 1) * 7 + dxi]));
    float wt[7];
    #pragma unroll
    for (int i = 0; i < 7; ++i) wt[i] = sgpr_f(w_s[42 + i]);
    __syncthreads();                         // staging complete too

    const int tx = t & 7, ty = t >> 3;       // 8 x 32
    const int ox = tx << 4;                  // 16-wide strip: 0,16,...,112
    float acc[16];
    #pragma unroll
    for (int j = 0; j < 16; ++j) acc[j] = 0.f;

    // tap half h = 7 + 3*dxi + j (j=0..15, dxi=0..6) -> h in 7..40; dw 0..20.
    #pragma unroll
    for (int p = 0; p < 3; ++p) {
        const int rA = ty + 6 * p;           // dyi=2p (lr <= 31+12 = 43)
        const unsigned* lA = &lds[rA * C7SD + (tx << 3)];
        const unsigned* lB = &lds[(rA + 3) * C7SD + (tx << 3)];
        unsigned hA[21], hB[21];
        #pragma unroll
        for (int i = 0; i < 21; ++i) hA[i] = lA[i];
        #pragma unroll
        for (int i = 0; i < 21; ++i) hB[i] = lB[i];
        unsigned pr[34];                     // s = i+7, i=0..33
        #pragma unroll
        for (int i = 0; i < 34; ++i) {
            const int s = i + 7, k = s >> 1;
            pr[i] = __builtin_amdgcn_perm(hB[k], hA[k],
                                          (s & 1) ? 0x07060302u : 0x05040100u);
        }
        #pragma unroll
        for (int dxi = 0; dxi < 7; ++dxi) {
            const unsigned wp = wpk[p * 7 + dxi];
            #pragma unroll
            for (int j = 0; j < 16; ++j)
                dot2_h(acc[j], wp, pr[3 * dxi + j]);
        }
    }
    // tail: dyi = 6 (lr = ty+18 <= 49)
    {
        const unsigned* lp = &lds[(ty + 18) * C7SD + (tx << 3)];
        unsigned hbuf[21];
        #pragma unroll
        for (int i = 0; i < 21; ++i) hbuf[i] = lp[i];
        #pragma unroll
        for (int dxi = 0; dxi < 7; ++dxi) {
            const float wv = wt[dxi];
            const int o = 7 + 3 * dxi;
            #pragma unroll
            for (int j = 0; j < 16; ++j) {
                const int h = o + j;
                fma_mix_h(acc[j], wv, hbuf[h >> 1], h & 1);
            }
        }
    }

    const float bs = bias[c];
    __half* op = attn1 + (size_t)plane * HW + (size_t)(oy0 + ty) * PW + ox0 + ox;
    #pragma unroll
    for (int q = 0; q < 2; ++q) {
        float g[8];
        #pragma unroll
        for (int j = 0; j < 8; ++j) g[j] = gelu_f(acc[q * 8 + j] + bs);
        uint4 st;
        st.x = pack2h(g[0], g[1]); st.y = pack2h(g[2], g[3]);
        st.z = pack2h(g[4], g[5]); st.w = pack2h(g[6], g[7]);
        *reinterpret_cast<uint4*>(op + (q << 3)) = st;
    }
}

// -------- K5: 1x1 channel mix + bias, then out = x * attn ---------------------
// (R20 version: 128-pixel chunks, dot2 channel-pairing, async x-load — unchanged)
__global__ __launch_bounds__(256) void k_mix(const __half* __restrict__ attn1,
                                             const float* __restrict__ wpm,
                                             const float* __restrict__ bp,
                                             const float* __restrict__ x,
                                             float* __restrict__ out) {
    __shared__ __half A_s[64][128];          // 16 KB
    __shared__ unsigned w2_s[32][64];        // 8 KB: (c-pair) x (o), f16x2
    const int t = threadIdx.x;
    const int blk = blockIdx.x;
    const int b = blk >> 9;
    const int p0g = (blk & 511) << 7;        // 128-pixel chunk
    const int o0 = (t >> 4) << 2;            // 4 outputs
    const int p0 = (t & 15) << 3;            // 8 pixels

    float4 xv0[4], xv1[4];
    #pragma unroll
    for (int oo = 0; oo < 4; ++oo) {
        const size_t base = (size_t)(b * 64 + o0 + oo) * HW + p0g + p0;
        xv0[oo] = *reinterpret_cast<const float4*>(x + base);
        xv1[oo] = *reinterpret_cast<const float4*>(x + base + 4);
    }

    #pragma unroll
    for (int it = 0; it < 4; ++it) {
        const int idx = it * 256 + t;        // 1024 uint4 = 64 rows x 16
        const int row = idx >> 4;
        const int off = (idx & 15) << 3;
        uint4 u = *reinterpret_cast<const uint4*>(attn1 + (size_t)(b * 64 + row) * HW + p0g + off);
        *reinterpret_cast<uint4*>(&A_s[row][off]) = u;
    }
    #pragma unroll
    for (int j = 0; j < 8; ++j) {
        const int idx = j * 256 + t;         // 2048 entries
        const int oo = idx >> 5;
        const int cc2 = idx & 31;
        w2_s[cc2][oo] = pack2h(wpm[oo * 64 + 2 * cc2], wpm[oo * 64 + 2 * cc2 + 1]);
    }
    __syncthreads();
    float acc[4][8];
    #pragma unroll
    for (int i = 0; i < 4; ++i)
        #pragma unroll
        for (int j = 0; j < 8; ++j) acc[i][j] = 0.f;
    #pragma unroll 4
    for (int cc2 = 0; cc2 < 32; ++cc2) {
        uint4 a0 = *reinterpret_cast<const uint4*>(&A_s[2 * cc2][p0]);
        uint4 a1 = *reinterpret_cast<const uint4*>(&A_s[2 * cc2 + 1][p0]);
        const unsigned a0w[4] = {a0.x, a0.y, a0.z, a0.w};
        const unsigned a1w[4] = {a1.x, a1.y, a1.z, a1.w};
        unsigned pr[8];
        #pragma unroll
        for (int j = 0; j < 8; ++j)
            pr[j] = __builtin_amdgcn_perm(a1w[j >> 1], a0w[j >> 1],
                                          (j & 1) ? 0x07060302u : 0x05040100u);
        uint4 wv0 = *reinterpret_cast<const uint4*>(&w2_s[cc2][o0]);
        const unsigned wv[4] = {wv0.x, wv0.y, wv0.z, wv0.w};
        #pragma unroll
        for (int oo = 0; oo < 4; ++oo) {
            const unsigned wvv = wv[oo];
            #pragma unroll
            for (int pp = 0; pp < 8; ++pp)
                dot2_hv(acc[oo][pp], wvv, pr[pp]);
        }
    }
    #pragma unroll
    for (int oo = 0; oo < 4; ++oo) {
        const int o = o0 + oo;
        const float bb = bp[o];
        const size_t base = (size_t)(b * 64 + o) * HW + p0g + p0;
        float4 r0, r1;
        r0.x = xv0[oo].x * (acc[oo][0] + bb); r0.y = xv0[oo].y * (acc[oo][1] + bb);
        r0.z = xv0[oo].z * (acc[oo][2] + bb); r0.w = xv0[oo].w * (acc[oo][3] + bb);
        r1.x = xv1[oo].x * (acc[oo][4] + bb); r1.y = xv1[oo].y * (acc[oo][5] + bb);
        r1.z = xv1[oo].z * (acc[oo][6] + bb); r1.w = xv1[oo].w * (acc[oo][7] + bb);
        *reinterpret_cast<float4*>(out + base) = r0;
        *reinterpret_cast<float4*>(out + base + 4) = r1;
    }
}

extern "C" void kernel_launch(void* const* d_in, const int* in_sizes, int n_in,
                              void* d_out, int out_size, void* d_ws, size_t ws_size,
                              hipStream_t stream) {
    const float* x   = (const float*)d_in[0];
    const float* w0  = (const float*)d_in[1];
    const float* b0  = (const float*)d_in[2];
    const float* r0w = (const float*)d_in[3];
    const float* r0b = (const float*)d_in[4];
    const float* w1  = (const float*)d_in[5];
    const float* b1  = (const float*)d_in[6];
    const float* r1w = (const float*)d_in[7];
    const float* r1b = (const float*)d_in[8];
    const float* wpm = (const float*)d_in[9];
    const float* bp  = (const float*)d_in[10];
    float* out = (float*)d_out;

    // workspace layout (needs ~134.3 MB)
    char* ws = (char*)d_ws;
    __half* attn0   = (__half*)(ws);                       // 64 MB
    __half* attn1   = (__half*)(ws + 67108864);            // 64 MB
    float* partial0 = (float*)(ws + 134217728);            // 2048 f32
    float* tilesum1 = (float*)(ws + 134217728 + 16384);    // 4096 f32

    k_pool_x<<<2048, 256, 0, stream>>>(x, partial0);
    k_conv5<<<4096, 256, 0, stream>>>(x, partial0, r0w, r0b, w0, b0, attn0, tilesum1);
    k_conv7<<<8192, 256, 0, stream>>>(attn0, tilesum1, r1w, r1b, w1, b1, attn1);
    k_mix<<<4096, 256, 0, stream>>>(attn1, wpm, bp, x, out);
}

// Round 22
// 224.022 us; speedup vs baseline: 1.0222x; 1.0222x over previous
//
#include <hip/hip_runtime.h>
#include <hip/hip_fp16.h>

#define HW 65536
#define PW 256        // plane width
#define C7SD 85       // conv7 LDS row stride in DWORDS (odd -> 64 lanes hit 32 banks)
#define C5SD 73       // conv5 LDS row stride in DWORDS (odd)

// Fast exact-gelu: erf via Abramowitz-Stegun 7.1.26 (|err| <= 1.5e-7).
__device__ __forceinline__ float gelu_f(float v) {
    float ax = fabsf(v) * 0.7071067811865476f;
    float t  = 1.0f / (1.0f + 0.3275911f * ax);
    float p  = t * (0.254829592f + t * (-0.284496736f + t * (1.421413741f
             + t * (-1.453152027f + t * 1.061405429f))));
    float e  = 1.0f - p * __expf(-ax * ax);
    e = copysignf(e, v);
    return 0.5f * v * (1.0f + e);
}

__device__ __forceinline__ unsigned pack2h(float a, float b) {
    __half2 h = __floats2half2_rn(a, b);
    return *reinterpret_cast<unsigned*>(&h);
}

__device__ __forceinline__ float sgpr_f(float v) {
    union { float f; int i; } u;
    u.f = v;
    u.i = __builtin_amdgcn_readfirstlane(u.i);
    return u.f;
}

// acc(f32) += w(f32) * f16-half of h2 (packed u32), via v_fma_mix_f32 op_sel.
__device__ __forceinline__ void fma_mix_h(float& acc, float w, unsigned h2, int sel) {
    if (sel == 0)
        asm("v_fma_mix_f32 %0, %1, %2, %0 op_sel:[0,0,0] op_sel_hi:[0,1,0]"
            : "+v"(acc) : "v"(w), "v"(h2));
    else
        asm("v_fma_mix_f32 %0, %1, %2, %0 op_sel:[0,1,0] op_sel_hi:[0,1,0]"
            : "+v"(acc) : "v"(w), "v"(h2));
}

// acc(f32) += wpk.lo*pr.lo + wpk.hi*pr.hi (f16 pairs, f32 accumulate)
__device__ __forceinline__ void dot2_h(float& acc, unsigned wpk, unsigned pr) {
    asm("v_dot2_f32_f16 %0, %1, %2, %0" : "+v"(acc) : "s"(wpk), "v"(pr));
}
__device__ __forceinline__ void dot2_hv(float& acc, unsigned wpk, unsigned pr) {
    asm("v_dot2_f32_f16 %0, %1, %2, %0" : "+v"(acc) : "v"(wpk), "v"(pr));
}

// ---------------- K0: pool x over H,W (partial sums, 4 blocks per plane) ------
__global__ __launch_bounds__(256) void k_pool_x(const float* __restrict__ x,
                                                float* __restrict__ partial) {
    __shared__ float red[256];
    const int t = threadIdx.x;
    const int blk = blockIdx.x;              // plane*4 + quarter
    const float* p = x + (size_t)blk * 16384;
    float s = 0.f;
    #pragma unroll
    for (int i = 0; i < 16; ++i) {
        float4 v = *reinterpret_cast<const float4*>(p + (i * 256 + t) * 4);
        s += v.x + v.y + v.z + v.w;
    }
    red[t] = s;
    __syncthreads();
    for (int off = 128; off > 0; off >>= 1) {
        if (t < off) red[t] += red[t + off];
        __syncthreads();
    }
    if (t == 0) partial[blk] = red[0];
}

// Fused per-block routing (same reduction order as standalone k_route_mix).
__device__ __forceinline__ void route_block(const float* __restrict__ partial,
                                            const float* __restrict__ rw,
                                            const float* __restrict__ rb,
                                            const float* __restrict__ wexp,
                                            int b, int c, int taps, int parts, int t,
                                            float* pool_s, float* r_s, float* w_s) {
    if (t < 64) {
        float s = 0.f;
        for (int q = 0; q < parts; ++q) s += partial[(b * 64 + t) * parts + q];
        pool_s[t] = s * (1.0f / 65536.0f);
    }
    __syncthreads();
    if (t < 3) {
        float z = rb[t];
        #pragma unroll
        for (int i = 0; i < 64; ++i) z += pool_s[i] * rw[t * 64 + i];
        r_s[t] = 1.0f / (1.0f + expf(-z));
    }
    __syncthreads();
    if (t < taps) {
        w_s[t] = r_s[0] * wexp[(0 * 64 + c) * taps + t] +
                 r_s[1] * wexp[(1 * 64 + c) * taps + t] +
                 r_s[2] * wexp[(2 * 64 + c) * taps + t];
    }
    __syncthreads();
}

// -------- K2: depthwise 5x5 pad2 + bias + gelu -> fp16, with tile sums --------
// (R19 version: dot2 dy-pairing, fp16 LDS, odd stride — unchanged)
__global__ __launch_bounds__(256, 3) void k_conv5(const float* __restrict__ x,
                                                  const float* __restrict__ partial,
                                                  const float* __restrict__ rw,
                                                  const float* __restrict__ rb,
                                                  const float* __restrict__ wexp,
                                                  const float* __restrict__ bias,
                                                  __half* __restrict__ attn0,
                                                  float* __restrict__ tilesum) {
    __shared__ unsigned lds[68 * C5SD];      // 19856 B
    __shared__ float red[256];
    __shared__ float pool_s[64];
    __shared__ float r_s[3];
    __shared__ float w_s[25];
    const int blk = blockIdx.x;              // plane*8 + tile (64-row x 128-col)
    const int plane = blk >> 3;
    const int tile = blk & 7;
    const int b = plane >> 6;
    const int c = plane & 63;
    const int oy0 = (tile >> 1) << 6;        // 0,64,128,192
    const int ox0 = (tile & 1) << 7;         // 0,128
    const int t = threadIdx.x;
    const float* xp = x + (size_t)plane * HW;

    #pragma unroll
    for (int it = 0; it < 5; ++it) {
        const int idx = it * 256 + t;
        if (idx < 1224) {                    // 68*18
            const int lr = idx / 18;
            const int c8 = idx - lr * 18;
            const int gy = oy0 - 2 + lr;
            const int gx = ox0 - 8 + (c8 << 3);
            unsigned d0 = 0u, d1 = 0u, d2 = 0u, d3 = 0u;
            if ((unsigned)gy < 256u) {
                if ((unsigned)gx < 256u) {
                    float4 v = *reinterpret_cast<const float4*>(xp + gy * PW + gx);
                    d0 = pack2h(v.x, v.y); d1 = pack2h(v.z, v.w);
                }
                if ((unsigned)(gx + 4) < 256u) {
                    float4 v = *reinterpret_cast<const float4*>(xp + gy * PW + gx + 4);
                    d2 = pack2h(v.x, v.y); d3 = pack2h(v.z, v.w);
                }
            }
            unsigned* wp = &lds[lr * C5SD + (c8 << 2)];
            wp[0] = d0; wp[1] = d1; wp[2] = d2; wp[3] = d3;
        }
    }

    route_block(partial, rw, rb, wexp, b, c, 25, 4, t, pool_s, r_s, w_s);
    unsigned wpk[10];
    #pragma unroll
    for (int p = 0; p < 2; ++p)
        #pragma unroll
        for (int dx = 0; dx < 5; ++dx)
            wpk[p * 5 + dx] = (unsigned)__builtin_amdgcn_readfirstlane(
                (int)pack2h(w_s[(2 * p) * 5 + dx], w_s[(2 * p + 1) * 5 + dx]));
    float wt[5];
    #pragma unroll
    for (int i = 0; i < 5; ++i) wt[i] = sgpr_f(w_s[20 + i]);
    __syncthreads();

    const int tx = t & 3, ty = t >> 2;       // 4 x 64
    const int ox = tx << 5;                  // 32-wide strip: 0,32,64,96
    float acc[32];
    #pragma unroll
    for (int j = 0; j < 32; ++j) acc[j] = 0.f;

    #pragma unroll
    for (int p = 0; p < 2; ++p) {
        const int lrA = ty + 2 * p;          // dy=2p
        const unsigned* lA = &lds[lrA * C5SD + (tx << 4) + 3];
        const unsigned* lB = &lds[(lrA + 1) * C5SD + (tx << 4) + 3];
        unsigned hA[19], hB[19];
        #pragma unroll
        for (int i = 0; i < 19; ++i) hA[i] = lA[i];
        #pragma unroll
        for (int i = 0; i < 19; ++i) hB[i] = lB[i];
        unsigned pr[37];
        #pragma unroll
        for (int q = 0; q < 37; ++q)
            pr[q] = __builtin_amdgcn_perm(hB[q >> 1], hA[q >> 1],
                                          (q & 1) ? 0x07060302u : 0x05040100u);
        #pragma unroll
        for (int dx = 0; dx < 5; ++dx) {
            const unsigned wp = wpk[p * 5 + dx];
            #pragma unroll
            for (int j = 0; j < 32; ++j)
                dot2_h(acc[j], wp, pr[j + dx]);
        }
    }
    {
        const unsigned* lp = &lds[(ty + 4) * C5SD + (tx << 4) + 3];
        unsigned hbuf[19];
        #pragma unroll
        for (int i = 0; i < 19; ++i) hbuf[i] = lp[i];
        #pragma unroll
        for (int dx = 0; dx < 5; ++dx) {
            const float wv = wt[dx];
            #pragma unroll
            for (int j = 0; j < 32; ++j) {
                const int q = j + dx;
                fma_mix_h(acc[j], wv, hbuf[q >> 1], q & 1);
            }
        }
    }

    const float bs = bias[c];
    float lsum = 0.f;
    __half* op = attn0 + (size_t)plane * HW + (size_t)(oy0 + ty) * PW + ox0 + ox;
    #pragma unroll
    for (int q = 0; q < 4; ++q) {
        float g[8];
        #pragma unroll
        for (int j = 0; j < 8; ++j) {
            g[j] = gelu_f(acc[q * 8 + j] + bs);
            lsum += g[j];
        }
        uint4 st;
        st.x = pack2h(g[0], g[1]); st.y = pack2h(g[2], g[3]);
        st.z = pack2h(g[4], g[5]); st.w = pack2h(g[6], g[7]);
        *reinterpret_cast<uint4*>(op + (q << 3)) = st;
    }
    red[t] = lsum;
    __syncthreads();
    for (int off = 128; off > 0; off >>= 1) {
        if (t < off) red[t] += red[t + off];
        __syncthreads();
    }
    if (t == 0) tilesum[blk] = red[0];
}

// -------- K4: depthwise 7x7 dil3 pad9 + bias + gelu, fp16 -> fp16 -------------
// (R15/R19 version: dot2 row-pairing, odd-stride LDS, 64-row tiles — best
// measured config: 77.3us. R21's 32-row tile doubled occupancy but regressed
// to 83us: conv7 is VALU-issue-saturated, not latency-bound.)
__global__ __launch_bounds__(256, 3) void k_conv7(const __half* __restrict__ a0,
                                                  const float* __restrict__ tilesum,
                                                  const float* __restrict__ rw,
                                                  const float* __restrict__ rb,
                                                  const float* __restrict__ wexp,
                                                  const float* __restrict__ bias,
                                                  __half* __restrict__ attn1) {
    __shared__ unsigned lds[82 * C7SD];      // 27880 B
    __shared__ float pool_s[64];
    __shared__ float r_s[3];
    __shared__ float w_s[49];
    const int blk = blockIdx.x;              // plane*8 + tile (64-row x 128-col)
    const int plane = blk >> 3;
    const int tile = blk & 7;
    const int b = plane >> 6;
    const int c = plane & 63;
    const int oy0 = (tile >> 1) << 6;        // 0,64,128,192
    const int ox0 = (tile & 1) << 7;         // 0,128
    const int t = threadIdx.x;
    const __half* ap = a0 + (size_t)plane * HW;

    const uint4 z4 = make_uint4(0u, 0u, 0u, 0u);
    #pragma unroll
    for (int it = 0; it < 7; ++it) {
        const int idx = it * 256 + t;
        if (idx < 1722) {                    // 82*21
            const int lr = idx / 21;
            const int c8 = idx - lr * 21;
            const int gy = oy0 - 9 + lr;
            const int gx = ox0 - 16 + (c8 << 3);
            uint4 v = z4;
            if ((unsigned)gy < 256u && (unsigned)gx < 256u)
                v = *reinterpret_cast<const uint4*>(ap + gy * PW + gx);
            unsigned* wp = &lds[lr * C7SD + (c8 << 2)];
            wp[0] = v.x; wp[1] = v.y; wp[2] = v.z; wp[3] = v.w;
        }
    }

    route_block(tilesum, rw, rb, wexp, b, c, 49, 8, t, pool_s, r_s, w_s);
    unsigned wpk[21];
    #pragma unroll
    for (int p = 0; p < 3; ++p)
        #pragma unroll
        for (int dxi = 0; dxi < 7; ++dxi)
            wpk[p * 7 + dxi] = (unsigned)__builtin_amdgcn_readfirstlane(
                (int)pack2h(w_s[(2 * p) * 7 + dxi], w_s[(2 * p + 1) * 7 + dxi]));
    float wt[7];
    #pragma unroll
    for (int i = 0; i < 7; ++i) wt[i] = sgpr_f(w_s[42 + i]);
    __syncthreads();                         // staging complete too

    const int tx = t & 3, ty = t >> 2;       // 4 x 64
    const int ox = tx << 5;                  // 32-wide strip: 0,32,64,96
    float acc[32];
    #pragma unroll
    for (int j = 0; j < 32; ++j) acc[j] = 0.f;

    #pragma unroll
    for (int p = 0; p < 3; ++p) {
        const int rA = ty + 6 * p;
        const unsigned* lA = &lds[rA * C7SD + (tx << 4)];
        const unsigned* lB = &lds[(rA + 3) * C7SD + (tx << 4)];
        unsigned hA[32], hB[32];
        #pragma unroll
        for (int i = 0; i < 32; ++i) hA[i] = lA[i];
        #pragma unroll
        for (int i = 0; i < 32; ++i) hB[i] = lB[i];
        unsigned pr[50];
        #pragma unroll
        for (int i = 0; i < 50; ++i) {
            const int s = i + 7, k = s >> 1;
            pr[i] = __builtin_amdgcn_perm(hB[k], hA[k],
                                          (s & 1) ? 0x07060302u : 0x05040100u);
        }
        #pragma unroll
        for (int dxi = 0; dxi < 7; ++dxi) {
            const unsigned wp = wpk[p * 7 + dxi];
            #pragma unroll
            for (int j = 0; j < 32; ++j)
                dot2_h(acc[j], wp, pr[3 * dxi + j]);
        }
    }
    {
        const unsigned* lp = &lds[(ty + 18) * C7SD + (tx << 4)];
        unsigned hbuf[32];
        #pragma unroll
        for (int i = 0; i < 32; ++i) hbuf[i] = lp[i];
        #pragma unroll
        for (int dxi = 0; dxi < 7; ++dxi) {
            const float wv = wt[dxi];
            const int o = 7 + 3 * dxi;
            #pragma unroll
            for (int j = 0; j < 32; ++j) {
                const int h = o + j;
                fma_mix_h(acc[j], wv, hbuf[h >> 1], h & 1);
            }
        }
    }

    const float bs = bias[c];
    __half* op = attn1 + (size_t)plane * HW + (size_t)(oy0 + ty) * PW + ox0 + ox;
    #pragma unroll
    for (int q = 0; q < 4; ++q) {
        float g[8];
        #pragma unroll
        for (int j = 0; j < 8; ++j) g[j] = gelu_f(acc[q * 8 + j] + bs);
        uint4 st;
        st.x = pack2h(g[0], g[1]); st.y = pack2h(g[2], g[3]);
        st.z = pack2h(g[4], g[5]); st.w = pack2h(g[6], g[7]);
        *reinterpret_cast<uint4*>(op + (q << 3)) = st;
    }
}

// -------- K5: 1x1 channel mix + bias, then out = x * attn ---------------------
// (R20 version: 128-pixel chunks, dot2 channel-pairing, async x-load — unchanged)
__global__ __launch_bounds__(256) void k_mix(const __half* __restrict__ attn1,
                                             const float* __restrict__ wpm,
                                             const float* __restrict__ bp,
                                             const float* __restrict__ x,
                                             float* __restrict__ out) {
    __shared__ __half A_s[64][128];          // 16 KB
    __shared__ unsigned w2_s[32][64];        // 8 KB: (c-pair) x (o), f16x2
    const int t = threadIdx.x;
    const int blk = blockIdx.x;
    const int b = blk >> 9;
    const int p0g = (blk & 511) << 7;        // 128-pixel chunk
    const int o0 = (t >> 4) << 2;            // 4 outputs
    const int p0 = (t & 15) << 3;            // 8 pixels

    float4 xv0[4], xv1[4];
    #pragma unroll
    for (int oo = 0; oo < 4; ++oo) {
        const size_t base = (size_t)(b * 64 + o0 + oo) * HW + p0g + p0;
        xv0[oo] = *reinterpret_cast<const float4*>(x + base);
        xv1[oo] = *reinterpret_cast<const float4*>(x + base + 4);
    }

    #pragma unroll
    for (int it = 0; it < 4; ++it) {
        const int idx = it * 256 + t;        // 1024 uint4 = 64 rows x 16
        const int row = idx >> 4;
        const int off = (idx & 15) << 3;
        uint4 u = *reinterpret_cast<const uint4*>(attn1 + (size_t)(b * 64 + row) * HW + p0g + off);
        *reinterpret_cast<uint4*>(&A_s[row][off]) = u;
    }
    #pragma unroll
    for (int j = 0; j < 8; ++j) {
        const int idx = j * 256 + t;         // 2048 entries
        const int oo = idx >> 5;
        const int cc2 = idx & 31;
        w2_s[cc2][oo] = pack2h(wpm[oo * 64 + 2 * cc2], wpm[oo * 64 + 2 * cc2 + 1]);
    }
    __syncthreads();
    float acc[4][8];
    #pragma unroll
    for (int i = 0; i < 4; ++i)
        #pragma unroll
        for (int j = 0; j < 8; ++j) acc[i][j] = 0.f;
    #pragma unroll 4
    for (int cc2 = 0; cc2 < 32; ++cc2) {
        uint4 a0 = *reinterpret_cast<const uint4*>(&A_s[2 * cc2][p0]);
        uint4 a1 = *reinterpret_cast<const uint4*>(&A_s[2 * cc2 + 1][p0]);
        const unsigned a0w[4] = {a0.x, a0.y, a0.z, a0.w};
        const unsigned a1w[4] = {a1.x, a1.y, a1.z, a1.w};
        unsigned pr[8];
        #pragma unroll
        for (int j = 0; j < 8; ++j)
            pr[j] = __builtin_amdgcn_perm(a1w[j >> 1], a0w[j >> 1],
                                          (j & 1) ? 0x07060302u : 0x05040100u);
        uint4 wv0 = *reinterpret_cast<const uint4*>(&w2_s[cc2][o0]);
        const unsigned wv[4] = {wv0.x, wv0.y, wv0.z, wv0.w};
        #pragma unroll
        for (int oo = 0; oo < 4; ++oo) {
            const unsigned wvv = wv[oo];
            #pragma unroll
            for (int pp = 0; pp < 8; ++pp)
                dot2_hv(acc[oo][pp], wvv, pr[pp]);
        }
    }
    #pragma unroll
    for (int oo = 0; oo < 4; ++oo) {
        const int o = o0 + oo;
        const float bb = bp[o];
        const size_t base = (size_t)(b * 64 + o) * HW + p0g + p0;
        float4 r0, r1;
        r0.x = xv0[oo].x * (acc[oo][0] + bb); r0.y = xv0[oo].y * (acc[oo][1] + bb);
        r0.z = xv0[oo].z * (acc[oo][2] + bb); r0.w = xv0[oo].w * (acc[oo][3] + bb);
        r1.x = xv1[oo].x * (acc[oo][4] + bb); r1.y = xv1[oo].y * (acc[oo][5] + bb);
        r1.z = xv1[oo].z * (acc[oo][6] + bb); r1.w = xv1[oo].w * (acc[oo][7] + bb);
        *reinterpret_cast<float4*>(out + base) = r0;
        *reinterpret_cast<float4*>(out + base + 4) = r1;
    }
}

extern "C" void kernel_launch(void* const* d_in, const int* in_sizes, int n_in,
                              void* d_out, int out_size, void* d_ws, size_t ws_size,
                              hipStream_t stream) {
    const float* x   = (const float*)d_in[0];
    const float* w0  = (const float*)d_in[1];
    const float* b0  = (const float*)d_in[2];
    const float* r0w = (const float*)d_in[3];
    const float* r0b = (const float*)d_in[4];
    const float* w1  = (const float*)d_in[5];
    const float* b1  = (const float*)d_in[6];
    const float* r1w = (const float*)d_in[7];
    const float* r1b = (const float*)d_in[8];
    const float* wpm = (const float*)d_in[9];
    const float* bp  = (const float*)d_in[10];
    float* out = (float*)d_out;

    // workspace layout (needs ~134.3 MB)
    char* ws = (char*)d_ws;
    __half* attn0   = (__half*)(ws);                       // 64 MB
    __half* attn1   = (__half*)(ws + 67108864);            // 64 MB
    float* partial0 = (float*)(ws + 134217728);            // 2048 f32
    float* tilesum1 = (float*)(ws + 134217728 + 16384);    // 4096 f32

    k_pool_x<<<2048, 256, 0, stream>>>(x, partial0);
    k_conv5<<<4096, 256, 0, stream>>>(x, partial0, r0w, r0b, w0, b0, attn0, tilesum1);
    k_conv7<<<4096, 256, 0, stream>>>(attn0, tilesum1, r1w, r1b, w1, b1, attn1);
    k_mix<<<4096, 256, 0, stream>>>(attn1, wpm, bp, x, out);
}